// Round 13
// baseline (642.292 us; speedup 1.0000x reference)
//
#include <hip/hip_runtime.h>
#include <cstddef>

#define DD     256      // feature dim
#define NCODES 1024     // codebook size
#define MTOT   65536    // 8*8192 queries
#define MB     128      // rows per block
#define NB     128      // codes per tile
#define KC     32       // K-chunk
#define LSTR   132      // LDS row stride (128 + 4 pad)

// ====== XLA:CPU f32 replica helpers ========================================
// Ground truth = jax reference executed by XLA:CPU on the push host.
//  - jnp.sum(a*a, -1): XLA row-reduce -> fused mul+reduce, STRICT SEQUENTIAL
//    over d (no reassoc), with mul+add CONTRACTED to FMA by LLVM codegen:
//      acc = fma(a[d], a[d], acc), d = 0..255.
//  - einsum 'bnd,kd->bnk': Eigen sgemm custom-call -> per C element one
//    accumulator, k ascending, FMA chain (Eigen vectorizes across rows,
//    so per-element order is a scalar FMA chain).
//  - dist2 = (x2 - 2*xw) + w2 elementwise f32 (2*xw exact, combine L2R).
//  - argmin: sequential reduce -> first index wins ties.

__device__ __forceinline__ float xla_seq_fma_sumsq256(const float* __restrict__ a) {
    float acc = 0.f;
    #pragma unroll 8
    for (int d = 0; d < 256; ++d)
        acc = __builtin_fmaf(a[d], a[d], acc);   // strict sequential FMA
    return acc;
}

__device__ __forceinline__ float chain_fma_dot256(const float* __restrict__ x,
                                                  const float* __restrict__ w) {
    float acc = 0.f;
    #pragma unroll 8
    for (int d = 0; d < 256; ++d)
        acc = __builtin_fmaf(x[d], w[d], acc);   // Eigen: FMA chain, k ascending
    return acc;
}

// --- kernel 0: per-code squared norms, XLA-replica bits --------------------
__global__ __launch_bounds__(256) void w2_kernel(const float* __restrict__ W,
                                                 float* __restrict__ w2) {
    int c = blockIdx.x * 256 + threadIdx.x;
    if (c >= NCODES) return;
    w2[c] = xla_seq_fma_sumsq256(W + (size_t)c * DD);
}

// --- kernel 1: fused GEMM screening + top-2 + XLA-replica re-rank ----------
__global__ __launch_bounds__(256, 2) void vq_main(
    const float* __restrict__ X, const float* __restrict__ W,
    const float* __restrict__ w2g, float* __restrict__ out,
    float* __restrict__ dl)
{
    __shared__ __align__(16) float Al[KC][LSTR];   // A transposed: Al[k][row]
    __shared__ __align__(16) float Bl[KC][LSTR];   // B transposed: Bl[k][code]
    __shared__ float w2s[NCODES];
    __shared__ int   i1_s[MB];
    __shared__ int   i2_s[MB];
    __shared__ int   idx_s[MB];

    const int tid = threadIdx.x;
    const int tx  = tid & 15;
    const int ty  = tid >> 4;
    const int m0  = blockIdx.x * MB;

    for (int i = tid; i < NCODES; i += 256) w2s[i] = w2g[i];

    // per-thread top-2 per owned row (screening metric: w2 - 2*xw, f32 fast)
    float v1[8], v2[8];
    int   i1[8], i2[8];
    #pragma unroll
    for (int i = 0; i < 8; ++i) { v1[i] = 3.4e38f; v2[i] = 3.4e38f; i1[i] = 0; i2[i] = 0; }

    for (int nt = 0; nt < NCODES / NB; ++nt) {
        const int c0 = nt * NB;
        float acc[8][8];
        #pragma unroll
        for (int i = 0; i < 8; ++i) {
            #pragma unroll
            for (int j = 0; j < 8; ++j) acc[i][j] = 0.f;
        }

        for (int kt = 0; kt < DD / KC; ++kt) {
            __syncthreads();   // protect previous tile's readers
            #pragma unroll
            for (int l = 0; l < 4; ++l) {
                const int f   = tid + l * 256;   // 0..1023 float4 slots
                const int row = f >> 3;          // 0..127
                const int c4  = f & 7;
                const float4 av = *reinterpret_cast<const float4*>(
                    X + (size_t)(m0 + row) * DD + kt * KC + c4 * 4);
                const float4 bv = *reinterpret_cast<const float4*>(
                    W + (size_t)(c0 + row) * DD + kt * KC + c4 * 4);
                const int kk = c4 * 4;
                Al[kk + 0][row] = av.x; Al[kk + 1][row] = av.y;
                Al[kk + 2][row] = av.z; Al[kk + 3][row] = av.w;
                Bl[kk + 0][row] = bv.x; Bl[kk + 1][row] = bv.y;
                Bl[kk + 2][row] = bv.z; Bl[kk + 3][row] = bv.w;
            }
            __syncthreads();

            #pragma unroll 8
            for (int k = 0; k < KC; ++k) {
                const float4 a0 = *reinterpret_cast<const float4*>(&Al[k][ty * 4]);
                const float4 a1 = *reinterpret_cast<const float4*>(&Al[k][64 + ty * 4]);
                const float4 b0 = *reinterpret_cast<const float4*>(&Bl[k][tx * 4]);
                const float4 b1 = *reinterpret_cast<const float4*>(&Bl[k][64 + tx * 4]);
                const float a[8] = {a0.x, a0.y, a0.z, a0.w, a1.x, a1.y, a1.z, a1.w};
                const float b[8] = {b0.x, b0.y, b0.z, b0.w, b1.x, b1.y, b1.z, b1.w};
                #pragma unroll
                for (int i = 0; i < 8; ++i) {
                    #pragma unroll
                    for (int j = 0; j < 8; ++j)
                        acc[i][j] = fmaf(a[i], b[j], acc[i][j]);
                }
            }
        }

        // epilogue: top-2 update (x^2 term constant over codes; ascending order)
        #pragma unroll
        for (int j = 0; j < 8; ++j) {
            const int cl = (j < 4) ? (tx * 4 + j) : (64 + tx * 4 + (j - 4));
            const int c  = c0 + cl;
            const float w2v = w2s[c];
            #pragma unroll
            for (int i = 0; i < 8; ++i) {
                const float d = w2v - 2.f * acc[i][j];
                if (d < v1[i])      { v2[i] = v1[i]; i2[i] = i1[i]; v1[i] = d; i1[i] = c; }
                else if (d < v2[i]) { v2[i] = d;     i2[i] = c; }
            }
        }
    }

    // cross-lane top-2 merge over the 16 tx threads per row
    #pragma unroll
    for (int i = 0; i < 8; ++i) {
        float a1v = v1[i], a2v = v2[i];
        int   a1i = i1[i], a2i = i2[i];
        #pragma unroll
        for (int m = 1; m <= 8; m <<= 1) {
            const float b1v = __shfl_xor(a1v, m);
            const int   b1i = __shfl_xor(a1i, m);
            const float b2v = __shfl_xor(a2v, m);
            const int   b2i = __shfl_xor(a2i, m);
            if (b1v < a1v || (b1v == a1v && b1i < a1i)) {
                if (b2v < a1v || (b2v == a1v && b2i < a1i)) { a2v = b2v; a2i = b2i; }
                else                                        { a2v = a1v; a2i = a1i; }
                a1v = b1v; a1i = b1i;
            } else {
                if (b1v < a2v || (b1v == a2v && b1i < a2i)) { a2v = b1v; a2i = b1i; }
            }
        }
        if (tx == 0) {
            const int r = (i < 4) ? (ty * 4 + i) : (64 + ty * 4 + (i - 4));
            i1_s[r] = a1i;
            i2_s[r] = a2i;
        }
    }
    __syncthreads();

    // XLA:CPU-replica re-rank: x2,w2 = sequential FMA reduce; xw = Eigen
    // FMA chain; dist2 = (x2 - 2*xw) + w2; argmin first-index.
    if (tid < MB) {
#pragma clang fp contract(off)
        const int r  = tid;
        int ca = i1_s[r], cb = i2_s[r];
        if (cb < ca) { const int t = ca; ca = cb; cb = t; }   // ascending index
        const float* xr = X + (size_t)(m0 + r) * DD;
        const float x2  = xla_seq_fma_sumsq256(xr);
        const float xwa = chain_fma_dot256(xr, W + (size_t)ca * DD);
        const float xwb = chain_fma_dot256(xr, W + (size_t)cb * DD);
        const float da  = (x2 - 2.0f * xwa) + w2s[ca];
        const float db  = (x2 - 2.0f * xwb) + w2s[cb];
        const bool pick_b = (db < da);            // tie keeps lower index (ca)
        const int pick = pick_b ? cb : ca;
        idx_s[r]   = pick;
        dl[m0 + r] = pick_b ? xwb : xwa;          // dot(x, code[argmin]) for loss
    }
    __syncthreads();

    // gather-write quantized rows (coalesced float4)
    const float4* W4 = reinterpret_cast<const float4*>(W);
    float4*       O4 = reinterpret_cast<float4*>(out);
    for (int e = tid; e < MB * (DD / 4); e += 256) {
        const int r  = e >> 6;
        const int c4 = e & 63;
        O4[(size_t)(m0 + r) * (DD / 4) + c4] =
            W4[(size_t)idx_s[r] * (DD / 4) + c4];
    }
}

// --- kernel 2: vq_loss = sum over softmax rows (axis = N per batch) --------
__global__ __launch_bounds__(256) void vq_loss_kernel(const float* __restrict__ dl,
                                                      float* __restrict__ outv) {
    __shared__ float red[256];
    const int tid = threadIdx.x;
    float total = 0.f;
    for (int b = 0; b < 8; ++b) {
        const float* row = dl + (size_t)b * 8192;
        float lm = -3.4e38f;
        for (int i = tid; i < 8192; i += 256) lm = fmaxf(lm, row[i]);
        red[tid] = lm; __syncthreads();
        for (int s = 128; s > 0; s >>= 1) {
            if (tid < s) red[tid] = fmaxf(red[tid], red[tid + s]);
            __syncthreads();
        }
        const float mx = red[0]; __syncthreads();

        float ls = 0.f;
        for (int i = tid; i < 8192; i += 256) ls += expf(row[i] - mx);
        red[tid] = ls; __syncthreads();
        for (int s = 128; s > 0; s >>= 1) {
            if (tid < s) red[tid] += red[tid + s];
            __syncthreads();
        }
        const float Z = red[0]; __syncthreads();

        float lc = 0.f;
        for (int i = tid; i < 8192; i += 256) lc += expf(row[i] - mx) / Z;
        red[tid] = lc; __syncthreads();
        for (int s = 128; s > 0; s >>= 1) {
            if (tid < s) red[tid] += red[tid + s];
            __syncthreads();
        }
        if (tid == 0) total += red[0];
        __syncthreads();
    }
    if (tid == 0) outv[0] = total;
}

// --- launch ----------------------------------------------------------------
extern "C" void kernel_launch(void* const* d_in, const int* in_sizes, int n_in,
                              void* d_out, int out_size, void* d_ws, size_t ws_size,
                              hipStream_t stream) {
    const float* X = (const float*)d_in[0];   // latents  [8,8192,256] f32
    const float* W = (const float*)d_in[1];   // weights  [1024,256]   f32
    float* out = (float*)d_out;               // quantized (65536*256) + vq_loss
    float* w2  = (float*)d_ws;                // [1024] XLA-replica code norms
    float* dlv = w2 + NCODES;                 // [65536] dot at argmin

    w2_kernel   <<<NCODES / 256, 256, 0, stream>>>(W, w2);
    vq_main     <<<MTOT / MB,    256, 0, stream>>>(X, W, w2, out, dlv);
    vq_loss_kernel<<<1,          256, 0, stream>>>(dlv, out + (size_t)MTOT * DD);
}

// Round 14
// 545.750 us; speedup vs baseline: 1.1769x; 1.1769x over previous
//
#include <hip/hip_runtime.h>
#include <cstddef>

#define DD     256      // feature dim
#define NCODES 1024     // codebook size
#define MTOT   65536    // 8*8192 queries
#define MB     64       // rows per block (1024 blocks -> 4 blocks/CU)
#define NB     128      // codes per tile
#define KC     32       // K-chunk
#define LSTRA  68       // LDS row stride for A (64 + 4 pad)
#define LSTRB  132      // LDS row stride for B (128 + 4 pad)

// ====== XLA:CPU f32 replica helpers (DO NOT TOUCH — verified r13) ==========
//  - x2/w2: strict sequential FMA reduce over d ascending.
//  - xw: Eigen FMA chain, k ascending.
//  - dist2 = (x2 - 2*xw) + w2, f32; argmin first-index.

__device__ __forceinline__ float xla_seq_fma_sumsq256(const float* __restrict__ a) {
    float acc = 0.f;
    #pragma unroll 8
    for (int d = 0; d < 256; ++d)
        acc = __builtin_fmaf(a[d], a[d], acc);
    return acc;
}

__device__ __forceinline__ float chain_fma_dot256(const float* __restrict__ x,
                                                  const float* __restrict__ w) {
    float acc = 0.f;
    #pragma unroll 8
    for (int d = 0; d < 256; ++d)
        acc = __builtin_fmaf(x[d], w[d], acc);
    return acc;
}

// --- kernel 0: per-code squared norms, XLA-replica bits --------------------
__global__ __launch_bounds__(256) void w2_kernel(const float* __restrict__ W,
                                                 float* __restrict__ w2) {
    int c = blockIdx.x * 256 + threadIdx.x;
    if (c >= NCODES) return;
    w2[c] = xla_seq_fma_sumsq256(W + (size_t)c * DD);
}

// --- kernel 1: fused GEMM screening + top-2 + XLA-replica re-rank ----------
// 64 rows x 128-code tiles, 16x16 threads, 4x8 register tile each.
__global__ __launch_bounds__(256, 4) void vq_main(
    const float* __restrict__ X, const float* __restrict__ W,
    const float* __restrict__ w2g, float* __restrict__ out,
    float* __restrict__ dl)
{
    __shared__ __align__(16) float Al[KC][LSTRA];  // A transposed: Al[k][row]
    __shared__ __align__(16) float Bl[KC][LSTRB];  // B transposed: Bl[k][code]
    __shared__ float w2s[NCODES];
    __shared__ int   i1_s[MB];
    __shared__ int   i2_s[MB];
    __shared__ int   idx_s[MB];

    const int tid = threadIdx.x;
    const int tx  = tid & 15;
    const int ty  = tid >> 4;
    const int m0  = blockIdx.x * MB;

    for (int i = tid; i < NCODES; i += 256) w2s[i] = w2g[i];

    // per-thread top-2 per owned row (screening metric: w2 - 2*xw, f32 fast)
    float v1[4], v2[4];
    int   i1[4], i2[4];
    #pragma unroll
    for (int i = 0; i < 4; ++i) { v1[i] = 3.4e38f; v2[i] = 3.4e38f; i1[i] = 0; i2[i] = 0; }

    for (int nt = 0; nt < NCODES / NB; ++nt) {
        const int c0 = nt * NB;
        float acc[4][8];
        #pragma unroll
        for (int i = 0; i < 4; ++i)
            #pragma unroll
            for (int j = 0; j < 8; ++j) acc[i][j] = 0.f;

        for (int kt = 0; kt < DD / KC; ++kt) {
            __syncthreads();   // protect previous tile's readers
            // stage A (64x32): 512 float4 slots, 2 per thread
            #pragma unroll
            for (int l = 0; l < 2; ++l) {
                const int f   = tid + l * 256;   // 0..511
                const int row = f >> 3;          // 0..63
                const int c4  = f & 7;
                const float4 av = *reinterpret_cast<const float4*>(
                    X + (size_t)(m0 + row) * DD + kt * KC + c4 * 4);
                const int kk = c4 * 4;
                Al[kk + 0][row] = av.x; Al[kk + 1][row] = av.y;
                Al[kk + 2][row] = av.z; Al[kk + 3][row] = av.w;
            }
            // stage B (128x32): 1024 float4 slots, 4 per thread
            #pragma unroll
            for (int l = 0; l < 4; ++l) {
                const int f   = tid + l * 256;   // 0..1023
                const int row = f >> 3;          // 0..127
                const int c4  = f & 7;
                const float4 bv = *reinterpret_cast<const float4*>(
                    W + (size_t)(c0 + row) * DD + kt * KC + c4 * 4);
                const int kk = c4 * 4;
                Bl[kk + 0][row] = bv.x; Bl[kk + 1][row] = bv.y;
                Bl[kk + 2][row] = bv.z; Bl[kk + 3][row] = bv.w;
            }
            __syncthreads();

            #pragma unroll 8
            for (int k = 0; k < KC; ++k) {
                const float4 a0 = *reinterpret_cast<const float4*>(&Al[k][ty * 4]);
                const float4 b0 = *reinterpret_cast<const float4*>(&Bl[k][tx * 4]);
                const float4 b1 = *reinterpret_cast<const float4*>(&Bl[k][64 + tx * 4]);
                const float a[4] = {a0.x, a0.y, a0.z, a0.w};
                const float b[8] = {b0.x, b0.y, b0.z, b0.w, b1.x, b1.y, b1.z, b1.w};
                #pragma unroll
                for (int i = 0; i < 4; ++i)
                    #pragma unroll
                    for (int j = 0; j < 8; ++j)
                        acc[i][j] = fmaf(a[i], b[j], acc[i][j]);
            }
        }

        // epilogue: top-2 update (x^2 term constant over codes; ascending order)
        #pragma unroll
        for (int j = 0; j < 8; ++j) {
            const int cl = (j < 4) ? (tx * 4 + j) : (64 + tx * 4 + (j - 4));
            const int c  = c0 + cl;
            const float w2v = w2s[c];
            #pragma unroll
            for (int i = 0; i < 4; ++i) {
                const float d = w2v - 2.f * acc[i][j];
                if (d < v1[i])      { v2[i] = v1[i]; i2[i] = i1[i]; v1[i] = d; i1[i] = c; }
                else if (d < v2[i]) { v2[i] = d;     i2[i] = c; }
            }
        }
    }

    // cross-lane top-2 merge over the 16 tx threads per row
    #pragma unroll
    for (int i = 0; i < 4; ++i) {
        float a1v = v1[i], a2v = v2[i];
        int   a1i = i1[i], a2i = i2[i];
        #pragma unroll
        for (int m = 1; m <= 8; m <<= 1) {
            const float b1v = __shfl_xor(a1v, m);
            const int   b1i = __shfl_xor(a1i, m);
            const float b2v = __shfl_xor(a2v, m);
            const int   b2i = __shfl_xor(a2i, m);
            if (b1v < a1v || (b1v == a1v && b1i < a1i)) {
                if (b2v < a1v || (b2v == a1v && b2i < a1i)) { a2v = b2v; a2i = b2i; }
                else                                        { a2v = a1v; a2i = a1i; }
                a1v = b1v; a1i = b1i;
            } else {
                if (b1v < a2v || (b1v == a2v && b1i < a2i)) { a2v = b1v; a2i = b1i; }
            }
        }
        if (tx == 0) {
            const int r = ty * 4 + i;
            i1_s[r] = a1i;
            i2_s[r] = a2i;
        }
    }
    __syncthreads();

    // XLA:CPU-replica re-rank (verified r13): x2 = seq FMA reduce;
    // xw = FMA chain; dist2 = (x2 - 2*xw) + w2; argmin first-index.
    if (tid < MB) {
#pragma clang fp contract(off)
        const int r  = tid;
        int ca = i1_s[r], cb = i2_s[r];
        if (cb < ca) { const int t = ca; ca = cb; cb = t; }   // ascending index
        const float* xr = X + (size_t)(m0 + r) * DD;
        const float x2  = xla_seq_fma_sumsq256(xr);
        const float xwa = chain_fma_dot256(xr, W + (size_t)ca * DD);
        const float xwb = chain_fma_dot256(xr, W + (size_t)cb * DD);
        const float da  = (x2 - 2.0f * xwa) + w2s[ca];
        const float db  = (x2 - 2.0f * xwb) + w2s[cb];
        const bool pick_b = (db < da);            // tie keeps lower index (ca)
        const int pick = pick_b ? cb : ca;
        idx_s[r]   = pick;
        dl[m0 + r] = pick_b ? xwb : xwa;          // dot(x, code[argmin]) for loss
    }
    __syncthreads();

    // gather-write quantized rows (coalesced float4)
    const float4* W4 = reinterpret_cast<const float4*>(W);
    float4*       O4 = reinterpret_cast<float4*>(out);
    for (int e = tid; e < MB * (DD / 4); e += 256) {
        const int r  = e >> 6;
        const int c4 = e & 63;
        O4[(size_t)(m0 + r) * (DD / 4) + c4] =
            W4[(size_t)idx_s[r] * (DD / 4) + c4];
    }
}

// --- kernel 2a: per-batch softmax sum (8 blocks, one per batch) ------------
__global__ __launch_bounds__(256) void vq_loss_partial(const float* __restrict__ dl,
                                                       float* __restrict__ partial) {
    __shared__ float red[256];
    const int tid = threadIdx.x;
    const int b   = blockIdx.x;
    const float* row = dl + (size_t)b * 8192;

    float lm = -3.4e38f;
    for (int i = tid; i < 8192; i += 256) lm = fmaxf(lm, row[i]);
    red[tid] = lm; __syncthreads();
    for (int s = 128; s > 0; s >>= 1) {
        if (tid < s) red[tid] = fmaxf(red[tid], red[tid + s]);
        __syncthreads();
    }
    const float mx = red[0]; __syncthreads();

    float ls = 0.f;
    for (int i = tid; i < 8192; i += 256) ls += expf(row[i] - mx);
    red[tid] = ls; __syncthreads();
    for (int s = 128; s > 0; s >>= 1) {
        if (tid < s) red[tid] += red[tid + s];
        __syncthreads();
    }
    const float Z = red[0]; __syncthreads();

    float lc = 0.f;
    for (int i = tid; i < 8192; i += 256) lc += expf(row[i] - mx) / Z;
    red[tid] = lc; __syncthreads();
    for (int s = 128; s > 0; s >>= 1) {
        if (tid < s) red[tid] += red[tid + s];
        __syncthreads();
    }
    if (tid == 0) partial[b] = red[0];
}

// --- kernel 2b: final sum of 8 partials ------------------------------------
__global__ void vq_loss_final(const float* __restrict__ partial,
                              float* __restrict__ outv) {
    if (threadIdx.x == 0) {
        float t = 0.f;
        for (int b = 0; b < 8; ++b) t += partial[b];
        outv[0] = t;
    }
}

// --- launch ----------------------------------------------------------------
extern "C" void kernel_launch(void* const* d_in, const int* in_sizes, int n_in,
                              void* d_out, int out_size, void* d_ws, size_t ws_size,
                              hipStream_t stream) {
    const float* X = (const float*)d_in[0];   // latents  [8,8192,256] f32
    const float* W = (const float*)d_in[1];   // weights  [1024,256]   f32
    float* out = (float*)d_out;               // quantized (65536*256) + vq_loss
    float* w2      = (float*)d_ws;            // [1024]  XLA-replica code norms
    float* dlv     = w2 + NCODES;             // [65536] dot at argmin
    float* partial = dlv + MTOT;              // [8]     per-batch loss

    w2_kernel      <<<NCODES / 256, 256, 0, stream>>>(W, w2);
    vq_main        <<<MTOT / MB,    256, 0, stream>>>(X, W, w2, out, dlv);
    vq_loss_partial<<<8,            256, 0, stream>>>(dlv, partial);
    vq_loss_final  <<<1,             64, 0, stream>>>(partial, out + (size_t)MTOT * DD);
}

// Round 15
// 499.091 us; speedup vs baseline: 1.2869x; 1.0935x over previous
//
#include <hip/hip_runtime.h>
#include <cstddef>

#define DD     256      // feature dim
#define NCODES 1024     // codebook size
#define MTOT   65536    // 8*8192 queries
#define MB     128      // rows per block
#define NBT    256      // codes per tile (4 tiles cover the codebook)
#define KC     32       // K-chunk
#define ASTR   132      // A k-row stride (128 rows + 4 pad)
#define BSTR   324      // B k-row stride (16 blocks x 20 floats + 4 pad)

// ====== XLA:CPU f32 replica helpers (DO NOT TOUCH — verified r13) ==========
__device__ __forceinline__ float xla_seq_fma_sumsq256(const float* __restrict__ a) {
    float acc = 0.f;
    #pragma unroll 8
    for (int d = 0; d < 256; ++d)
        acc = __builtin_fmaf(a[d], a[d], acc);
    return acc;
}

__device__ __forceinline__ float chain_fma_dot256(const float* __restrict__ x,
                                                  const float* __restrict__ w) {
    float acc = 0.f;
    #pragma unroll 8
    for (int d = 0; d < 256; ++d)
        acc = __builtin_fmaf(x[d], w[d], acc);
    return acc;
}

// --- kernel 0: per-code squared norms, XLA-replica bits --------------------
__global__ __launch_bounds__(256) void w2_kernel(const float* __restrict__ W,
                                                 float* __restrict__ w2) {
    int c = blockIdx.x * 256 + threadIdx.x;
    if (c >= NCODES) return;
    w2[c] = xla_seq_fma_sumsq256(W + (size_t)c * DD);
}

// --- kernel 1: fused GEMM screening + top-2 + XLA-replica re-rank ----------
// 128 rows x 256-code tiles; 256 threads as (ty=tid>>4 -> 8 rows each,
// tx=tid&15 -> 16 codes each); 8x16 register tile; LDS layouts engineered
// for conflict-free ds_read_b128.
__global__ __launch_bounds__(256, 2) void vq_main(
    const float* __restrict__ X, const float* __restrict__ W,
    const float* __restrict__ w2g, float* __restrict__ out,
    float* __restrict__ dl)
{
    __shared__ __align__(16) float Al[KC * ASTR];   // Al[k*ASTR + row]
    __shared__ __align__(16) float Bl[KC * BSTR];   // Bl[k*BSTR + (c>>4)*20 + (c&15)]
    __shared__ float w2s[NCODES];
    __shared__ int   i1_s[MB];
    __shared__ int   i2_s[MB];
    __shared__ int   idx_s[MB];

    const int tid = threadIdx.x;
    const int tx  = tid & 15;
    const int ty  = tid >> 4;
    const int m0  = blockIdx.x * MB;

    for (int i = tid; i < NCODES; i += 256) w2s[i] = w2g[i];

    // per-thread top-2 per owned row (rows r = ty*8 + i)
    float v1[8], v2[8];
    int   i1[8], i2[8];
    #pragma unroll
    for (int i = 0; i < 8; ++i) { v1[i] = 3.4e38f; v2[i] = 3.4e38f; i1[i] = 0; i2[i] = 0; }

    for (int nt = 0; nt < NCODES / NBT; ++nt) {
        const int c0 = nt * NBT;
        float acc[8][16];
        #pragma unroll
        for (int i = 0; i < 8; ++i)
            #pragma unroll
            for (int j = 0; j < 16; ++j) acc[i][j] = 0.f;

        for (int kt = 0; kt < DD / KC; ++kt) {
            __syncthreads();   // protect previous tile's readers
            // stage A (128 rows x 32 k): 1024 float4 slots, 4/thread, coalesced
            #pragma unroll
            for (int l = 0; l < 4; ++l) {
                const int f   = tid + l * 256;
                const int row = f >> 3;          // 0..127
                const int c4  = f & 7;           // float4 chunk along k
                const float4 av = *reinterpret_cast<const float4*>(
                    X + (size_t)(m0 + row) * DD + kt * KC + c4 * 4);
                float* dst = Al + row;
                dst[(c4 * 4 + 0) * ASTR] = av.x;
                dst[(c4 * 4 + 1) * ASTR] = av.y;
                dst[(c4 * 4 + 2) * ASTR] = av.z;
                dst[(c4 * 4 + 3) * ASTR] = av.w;
            }
            // stage B (256 codes x 32 k): 2048 slots, 8/thread, coalesced
            #pragma unroll
            for (int l = 0; l < 8; ++l) {
                const int f    = tid + l * 256;
                const int code = f >> 3;         // 0..255
                const int c4   = f & 7;
                const float4 bv = *reinterpret_cast<const float4*>(
                    W + (size_t)(c0 + code) * DD + kt * KC + c4 * 4);
                const int base = (code >> 4) * 20 + (code & 15);
                float* dst = Bl + base;
                dst[(c4 * 4 + 0) * BSTR] = bv.x;
                dst[(c4 * 4 + 1) * BSTR] = bv.y;
                dst[(c4 * 4 + 2) * BSTR] = bv.z;
                dst[(c4 * 4 + 3) * BSTR] = bv.w;
            }
            __syncthreads();

            #pragma unroll 4
            for (int k = 0; k < KC; ++k) {
                const float* ar = Al + k * ASTR + ty * 8;
                const float4 a0 = *reinterpret_cast<const float4*>(ar);
                const float4 a1 = *reinterpret_cast<const float4*>(ar + 4);
                const float* br = Bl + k * BSTR + tx * 20;
                const float4 b0 = *reinterpret_cast<const float4*>(br);
                const float4 b1 = *reinterpret_cast<const float4*>(br + 4);
                const float4 b2 = *reinterpret_cast<const float4*>(br + 8);
                const float4 b3 = *reinterpret_cast<const float4*>(br + 12);
                const float a[8]  = {a0.x, a0.y, a0.z, a0.w, a1.x, a1.y, a1.z, a1.w};
                const float b[16] = {b0.x, b0.y, b0.z, b0.w, b1.x, b1.y, b1.z, b1.w,
                                     b2.x, b2.y, b2.z, b2.w, b3.x, b3.y, b3.z, b3.w};
                #pragma unroll
                for (int i = 0; i < 8; ++i)
                    #pragma unroll
                    for (int j = 0; j < 16; ++j)
                        acc[i][j] = fmaf(a[i], b[j], acc[i][j]);
            }
        }

        // epilogue: top-2 update (x^2 constant over codes; ascending code order)
        #pragma unroll
        for (int j = 0; j < 16; ++j) {
            const int c  = c0 + tx * 16 + j;
            const float w2v = w2s[c];
            #pragma unroll
            for (int i = 0; i < 8; ++i) {
                const float d = w2v - 2.f * acc[i][j];
                if (d < v1[i])      { v2[i] = v1[i]; i2[i] = i1[i]; v1[i] = d; i1[i] = c; }
                else if (d < v2[i]) { v2[i] = d;     i2[i] = c; }
            }
        }
    }

    // cross-lane top-2 merge over the 16 tx threads sharing each row
    #pragma unroll
    for (int i = 0; i < 8; ++i) {
        float a1v = v1[i], a2v = v2[i];
        int   a1i = i1[i], a2i = i2[i];
        #pragma unroll
        for (int m = 1; m <= 8; m <<= 1) {
            const float b1v = __shfl_xor(a1v, m);
            const int   b1i = __shfl_xor(a1i, m);
            const float b2v = __shfl_xor(a2v, m);
            const int   b2i = __shfl_xor(a2i, m);
            if (b1v < a1v || (b1v == a1v && b1i < a1i)) {
                if (b2v < a1v || (b2v == a1v && b2i < a1i)) { a2v = b2v; a2i = b2i; }
                else                                        { a2v = a1v; a2i = a1i; }
                a1v = b1v; a1i = b1i;
            } else {
                if (b1v < a2v || (b1v == a2v && b1i < a2i)) { a2v = b1v; a2i = b1i; }
            }
        }
        if (tx == 0) {
            const int r = ty * 8 + i;
            i1_s[r] = a1i;
            i2_s[r] = a2i;
        }
    }
    __syncthreads();

    // XLA:CPU-replica re-rank (verified r13): x2 = seq FMA reduce;
    // xw = FMA chain; dist2 = (x2 - 2*xw) + w2; argmin first-index.
    if (tid < MB) {
#pragma clang fp contract(off)
        const int r  = tid;
        int ca = i1_s[r], cb = i2_s[r];
        if (cb < ca) { const int t = ca; ca = cb; cb = t; }   // ascending index
        const float* xr = X + (size_t)(m0 + r) * DD;
        const float x2  = xla_seq_fma_sumsq256(xr);
        const float xwa = chain_fma_dot256(xr, W + (size_t)ca * DD);
        const float xwb = chain_fma_dot256(xr, W + (size_t)cb * DD);
        const float da  = (x2 - 2.0f * xwa) + w2s[ca];
        const float db  = (x2 - 2.0f * xwb) + w2s[cb];
        const bool pick_b = (db < da);            // tie keeps lower index (ca)
        const int pick = pick_b ? cb : ca;
        idx_s[r]   = pick;
        dl[m0 + r] = pick_b ? xwb : xwa;          // dot(x, code[argmin]) for loss
    }
    __syncthreads();

    // gather-write quantized rows (coalesced float4)
    const float4* W4 = reinterpret_cast<const float4*>(W);
    float4*       O4 = reinterpret_cast<float4*>(out);
    #pragma unroll 4
    for (int e = tid; e < MB * (DD / 4); e += 256) {
        const int r  = e >> 6;
        const int c4 = e & 63;
        O4[(size_t)(m0 + r) * (DD / 4) + c4] =
            W4[(size_t)idx_s[r] * (DD / 4) + c4];
    }
}

// --- kernel 2a: per-batch softmax sum (8 blocks, one per batch) ------------
__global__ __launch_bounds__(256) void vq_loss_partial(const float* __restrict__ dl,
                                                       float* __restrict__ partial) {
    __shared__ float red[256];
    const int tid = threadIdx.x;
    const int b   = blockIdx.x;
    const float* row = dl + (size_t)b * 8192;

    float lm = -3.4e38f;
    for (int i = tid; i < 8192; i += 256) lm = fmaxf(lm, row[i]);
    red[tid] = lm; __syncthreads();
    for (int s = 128; s > 0; s >>= 1) {
        if (tid < s) red[tid] = fmaxf(red[tid], red[tid + s]);
        __syncthreads();
    }
    const float mx = red[0]; __syncthreads();

    float ls = 0.f;
    for (int i = tid; i < 8192; i += 256) ls += expf(row[i] - mx);
    red[tid] = ls; __syncthreads();
    for (int s = 128; s > 0; s >>= 1) {
        if (tid < s) red[tid] += red[tid + s];
        __syncthreads();
    }
    const float Z = red[0]; __syncthreads();

    float lc = 0.f;
    for (int i = tid; i < 8192; i += 256) lc += expf(row[i] - mx) / Z;
    red[tid] = lc; __syncthreads();
    for (int s = 128; s > 0; s >>= 1) {
        if (tid < s) red[tid] += red[tid + s];
        __syncthreads();
    }
    if (tid == 0) partial[b] = red[0];
}

// --- kernel 2b: final sum of 8 partials ------------------------------------
__global__ void vq_loss_final(const float* __restrict__ partial,
                              float* __restrict__ outv) {
    if (threadIdx.x == 0) {
        float t = 0.f;
        for (int b = 0; b < 8; ++b) t += partial[b];
        outv[0] = t;
    }
}

// --- launch ----------------------------------------------------------------
extern "C" void kernel_launch(void* const* d_in, const int* in_sizes, int n_in,
                              void* d_out, int out_size, void* d_ws, size_t ws_size,
                              hipStream_t stream) {
    const float* X = (const float*)d_in[0];   // latents  [8,8192,256] f32
    const float* W = (const float*)d_in[1];   // weights  [1024,256]   f32
    float* out = (float*)d_out;               // quantized (65536*256) + vq_loss
    float* w2      = (float*)d_ws;            // [1024]  XLA-replica code norms
    float* dlv     = w2 + NCODES;             // [65536] dot at argmin
    float* partial = dlv + MTOT;              // [8]     per-batch loss

    w2_kernel      <<<NCODES / 256, 256, 0, stream>>>(W, w2);
    vq_main        <<<MTOT / MB,    256, 0, stream>>>(X, W, w2, out, dlv);
    vq_loss_partial<<<8,            256, 0, stream>>>(dlv, partial);
    vq_loss_final  <<<1,             64, 0, stream>>>(partial, out + (size_t)MTOT * DD);
}

// Round 16
// 275.985 us; speedup vs baseline: 2.3273x; 1.8084x over previous
//
#include <hip/hip_runtime.h>
#include <cstddef>

#define DD     256      // feature dim
#define NCODES 1024     // codebook size
#define MTOT   65536    // 8*8192 queries
#define MB     64       // rows per block (1024 blocks)
#define WSTR   264      // Wl LDS row stride in bf16 units (256 + 8 pad)

typedef __attribute__((ext_vector_type(8))) short short8v;  // 8 bf16 (4 VGPR)
typedef __attribute__((ext_vector_type(4))) float f32x4;    // MFMA accum

// ====== XLA:CPU f32 replica helpers (DO NOT TOUCH — verified r13) ==========
__device__ __forceinline__ float xla_seq_fma_sumsq256(const float* __restrict__ a) {
    float acc = 0.f;
    #pragma unroll 8
    for (int d = 0; d < 256; ++d)
        acc = __builtin_fmaf(a[d], a[d], acc);
    return acc;
}

__device__ __forceinline__ float chain_fma_dot256(const float* __restrict__ x,
                                                  const float* __restrict__ w) {
    float acc = 0.f;
    #pragma unroll 8
    for (int d = 0; d < 256; ++d)
        acc = __builtin_fmaf(x[d], w[d], acc);
    return acc;
}

// ====== bf16 helpers (screening only — bits not correctness-critical) ======
__device__ __forceinline__ short bf16_rne(float f) {
    unsigned u = __builtin_bit_cast(unsigned, f);
    u = u + 0x7FFFu + ((u >> 16) & 1u);
    return (short)(u >> 16);
}
__device__ __forceinline__ unsigned pack_bf2(float lo, float hi) {
    return (unsigned)(unsigned short)bf16_rne(lo) |
           ((unsigned)(unsigned short)bf16_rne(hi) << 16);
}

// --- kernel 0: per-code squared norms, XLA-replica bits --------------------
__global__ __launch_bounds__(256) void w2_kernel(const float* __restrict__ W,
                                                 float* __restrict__ w2) {
    int c = blockIdx.x * 256 + threadIdx.x;
    if (c >= NCODES) return;
    w2[c] = xla_seq_fma_sumsq256(W + (size_t)c * DD);
}

// --- kernel 1: MFMA bf16 screening + top-4 + XLA-replica re-rank -----------
// 64 rows/block, 4 waves; wave w owns rows w*16..w*16+15 (full K=256 A-frags
// in registers). Codes looped in 64-wide tiles staged to LDS as bf16.
// mfma_f32_16x16x32_bf16: A/B lane l -> row/col l&15, k=(l>>4)*8+j;
// C/D: col=lane&15, row=(lane>>4)*4+reg (guide §3, m89/m92-verified).
__global__ __launch_bounds__(256, 2) void vq_main(
    const float* __restrict__ X, const float* __restrict__ W,
    const float* __restrict__ w2g, float* __restrict__ out,
    float* __restrict__ dl)
{
    __shared__ short Wl[64 * WSTR];        // bf16 W tile [code][d]
    __shared__ float w2s[NCODES];
    __shared__ float cv[MB][48];           // per-row screening candidates
    __shared__ int   ci[MB][48];
    __shared__ int   idx_s[MB];

    const int tid  = threadIdx.x;
    const int lane = tid & 63;
    const int wv   = tid >> 6;
    const int m0   = blockIdx.x * MB;
    const int lg   = lane & 15;            // col-in-frag / row-in-frag
    const int kb   = (lane >> 4) * 8;      // k base within 32-chunk

    for (int i = tid; i < NCODES; i += 256) w2s[i] = w2g[i];

    // A-frags: this wave's 16 rows, full K=256 (8 frags of 8 bf16)
    const int arow = m0 + wv * 16 + lg;
    short8v a_frags[8];
    #pragma unroll
    for (int kg = 0; kg < 8; ++kg) {
        const float* src = X + (size_t)arow * DD + kg * 32 + kb;
        const float4 x0 = *reinterpret_cast<const float4*>(src);
        const float4 x1 = *reinterpret_cast<const float4*>(src + 4);
        short8v s;
        s[0] = bf16_rne(x0.x); s[1] = bf16_rne(x0.y);
        s[2] = bf16_rne(x0.z); s[3] = bf16_rne(x0.w);
        s[4] = bf16_rne(x1.x); s[5] = bf16_rne(x1.y);
        s[6] = bf16_rne(x1.z); s[7] = bf16_rne(x1.w);
        a_frags[kg] = s;
    }

    // per-lane top-3 per owned row-reg (rows (lane>>4)*4 + rg)
    float v[4][3]; int vi[4][3];
    #pragma unroll
    for (int rg = 0; rg < 4; ++rg)
        #pragma unroll
        for (int j = 0; j < 3; ++j) { v[rg][j] = 3.4e38f; vi[rg][j] = 0; }

    for (int ct = 0; ct < NCODES / 64; ++ct) {
        const int c0 = ct * 64;
        __syncthreads();   // protect previous tile's readers
        // stage W tile (64 codes x 256 d) -> bf16 LDS, coalesced
        #pragma unroll
        for (int l = 0; l < 16; ++l) {
            const int f    = tid + l * 256;   // 0..4095
            const int code = f >> 6;
            const int d4   = f & 63;
            const float4 w4 = *reinterpret_cast<const float4*>(
                W + (size_t)(c0 + code) * DD + d4 * 4);
            unsigned* dst = reinterpret_cast<unsigned*>(&Wl[code * WSTR + d4 * 4]);
            dst[0] = pack_bf2(w4.x, w4.y);
            dst[1] = pack_bf2(w4.z, w4.w);
        }
        __syncthreads();

        f32x4 acc[4];
        const f32x4 z = {0.f, 0.f, 0.f, 0.f};
        #pragma unroll
        for (int cg = 0; cg < 4; ++cg) acc[cg] = z;

        #pragma unroll
        for (int kg = 0; kg < 8; ++kg) {
            #pragma unroll
            for (int cg = 0; cg < 4; ++cg) {
                const short8v b = *reinterpret_cast<const short8v*>(
                    &Wl[(cg * 16 + lg) * WSTR + kg * 32 + kb]);
                acc[cg] = __builtin_amdgcn_mfma_f32_16x16x32_bf16(
                    a_frags[kg], b, acc[cg], 0, 0, 0);
            }
        }

        // epilogue: dist = w2 - 2*xw, top-3 insert per row-reg
        #pragma unroll
        for (int cg = 0; cg < 4; ++cg) {
            const int c = c0 + cg * 16 + lg;
            const float w2v = w2s[c];
            #pragma unroll
            for (int rg = 0; rg < 4; ++rg) {
                const float d = __builtin_fmaf(-2.f, acc[cg][rg], w2v);
                if (d < v[rg][0]) {
                    v[rg][2] = v[rg][1]; vi[rg][2] = vi[rg][1];
                    v[rg][1] = v[rg][0]; vi[rg][1] = vi[rg][0];
                    v[rg][0] = d;        vi[rg][0] = c;
                } else if (d < v[rg][1]) {
                    v[rg][2] = v[rg][1]; vi[rg][2] = vi[rg][1];
                    v[rg][1] = d;        vi[rg][1] = c;
                } else if (d < v[rg][2]) {
                    v[rg][2] = d;        vi[rg][2] = c;
                }
            }
        }
    }

    // dump candidates: row r covered by 16 lanes (lg), each with top-3
    const int rbase = wv * 16 + (lane >> 4) * 4;
    #pragma unroll
    for (int rg = 0; rg < 4; ++rg)
        #pragma unroll
        for (int j = 0; j < 3; ++j) {
            cv[rbase + rg][lg * 3 + j] = v[rg][j];
            ci[rbase + rg][lg * 3 + j] = vi[rg][j];
        }
    __syncthreads();

    // top-4 of 48 by screening value, then bit-exact re-rank (r13 recipe)
    if (tid < MB) {
        float bv[4] = {3.4e38f, 3.4e38f, 3.4e38f, 3.4e38f};
        int   bi[4] = {0x7fffffff, 0x7fffffff, 0x7fffffff, 0x7fffffff};
        for (int j = 0; j < 48; ++j) {
            const float d = cv[tid][j];
            const int   c = ci[tid][j];
            if (d < bv[0] || (d == bv[0] && c < bi[0])) {
                bv[3]=bv[2]; bi[3]=bi[2]; bv[2]=bv[1]; bi[2]=bi[1];
                bv[1]=bv[0]; bi[1]=bi[0]; bv[0]=d; bi[0]=c;
            } else if (d < bv[1] || (d == bv[1] && c < bi[1])) {
                bv[3]=bv[2]; bi[3]=bi[2]; bv[2]=bv[1]; bi[2]=bi[1];
                bv[1]=d; bi[1]=c;
            } else if (d < bv[2] || (d == bv[2] && c < bi[2])) {
                bv[3]=bv[2]; bi[3]=bi[2]; bv[2]=d; bi[2]=c;
            } else if (d < bv[3] || (d == bv[3] && c < bi[3])) {
                bv[3]=d; bi[3]=c;
            }
        }
        // sort candidate ids ascending -> strict < re-rank = first-index ties
        #pragma unroll
        for (int a = 0; a < 3; ++a)
            #pragma unroll
            for (int b = 0; b < 3 - a; ++b)
                if (bi[b] > bi[b + 1]) { const int t = bi[b]; bi[b] = bi[b+1]; bi[b+1] = t; }
        {
#pragma clang fp contract(off)
            const float* xr = X + (size_t)(m0 + tid) * DD;
            const float x2 = xla_seq_fma_sumsq256(xr);
            float best = 3.4e38f; int pick = bi[0]; float pd = 0.f;
            #pragma unroll
            for (int t = 0; t < 4; ++t) {
                const int c = bi[t];
                const float xw = chain_fma_dot256(xr, W + (size_t)c * DD);
                const float dd = (x2 - 2.0f * xw) + w2s[c];
                if (dd < best) { best = dd; pick = c; pd = xw; }
            }
            idx_s[tid] = pick;
            dl[m0 + tid] = pd;
        }
    }
    __syncthreads();

    // gather-write quantized rows (coalesced float4)
    const float4* W4 = reinterpret_cast<const float4*>(W);
    float4*       O4 = reinterpret_cast<float4*>(out);
    #pragma unroll
    for (int l = 0; l < 16; ++l) {
        const int e  = tid + l * 256;   // 0..4095
        const int r  = e >> 6;
        const int c4 = e & 63;
        O4[(size_t)(m0 + r) * (DD / 4) + c4] =
            W4[(size_t)idx_s[r] * (DD / 4) + c4];
    }
}

// --- kernel 2a: per-batch softmax sum (8 blocks, one per batch) ------------
__global__ __launch_bounds__(256) void vq_loss_partial(const float* __restrict__ dl,
                                                       float* __restrict__ partial) {
    __shared__ float red[256];
    const int tid = threadIdx.x;
    const int b   = blockIdx.x;
    const float* row = dl + (size_t)b * 8192;

    float lm = -3.4e38f;
    for (int i = tid; i < 8192; i += 256) lm = fmaxf(lm, row[i]);
    red[tid] = lm; __syncthreads();
    for (int s = 128; s > 0; s >>= 1) {
        if (tid < s) red[tid] = fmaxf(red[tid], red[tid + s]);
        __syncthreads();
    }
    const float mx = red[0]; __syncthreads();

    float ls = 0.f;
    for (int i = tid; i < 8192; i += 256) ls += expf(row[i] - mx);
    red[tid] = ls; __syncthreads();
    for (int s = 128; s > 0; s >>= 1) {
        if (tid < s) red[tid] += red[tid + s];
        __syncthreads();
    }
    const float Z = red[0]; __syncthreads();

    float lc = 0.f;
    for (int i = tid; i < 8192; i += 256) lc += expf(row[i] - mx) / Z;
    red[tid] = lc; __syncthreads();
    for (int s = 128; s > 0; s >>= 1) {
        if (tid < s) red[tid] += red[tid + s];
        __syncthreads();
    }
    if (tid == 0) partial[b] = red[0];
}

// --- kernel 2b: final sum of 8 partials ------------------------------------
__global__ void vq_loss_final(const float* __restrict__ partial,
                              float* __restrict__ outv) {
    if (threadIdx.x == 0) {
        float t = 0.f;
        for (int b = 0; b < 8; ++b) t += partial[b];
        outv[0] = t;
    }
}

// --- launch ----------------------------------------------------------------
extern "C" void kernel_launch(void* const* d_in, const int* in_sizes, int n_in,
                              void* d_out, int out_size, void* d_ws, size_t ws_size,
                              hipStream_t stream) {
    const float* X = (const float*)d_in[0];   // latents  [8,8192,256] f32
    const float* W = (const float*)d_in[1];   // weights  [1024,256]   f32
    float* out = (float*)d_out;               // quantized (65536*256) + vq_loss
    float* w2      = (float*)d_ws;            // [1024]  XLA-replica code norms
    float* dlv     = w2 + NCODES;             // [65536] dot at argmin
    float* partial = dlv + MTOT;              // [8]     per-batch loss

    w2_kernel      <<<NCODES / 256, 256, 0, stream>>>(W, w2);
    vq_main        <<<MTOT / MB,    256, 0, stream>>>(X, W, w2, out, dlv);
    vq_loss_partial<<<8,            256, 0, stream>>>(dlv, partial);
    vq_loss_final  <<<1,             64, 0, stream>>>(partial, out + (size_t)MTOT * DD);
}